// Round 5
// baseline (327.155 us; speedup 1.0000x reference)
//
#include <hip/hip_runtime.h>
#include <stdint.h>

#define BB 4
#define CC 512
#define NN 4096
#define DQd 64

typedef unsigned short u16;
typedef unsigned int u32;
typedef __bf16 bf16x8 __attribute__((ext_vector_type(8)));
typedef float f32x4 __attribute__((ext_vector_type(4)));
typedef float f32x16 __attribute__((ext_vector_type(16)));

__device__ __forceinline__ u16 f2bf(float f) {
  union { float f; u32 u; } v; v.f = f;
  u32 r = v.u + 0x7FFFu + ((v.u >> 16) & 1u);
  return (u16)(r >> 16);
}

__device__ __forceinline__ bf16x8 ld_bf8(const u16* p) {
  return *reinterpret_cast<const bf16x8*>(p);
}

__device__ __forceinline__ f32x4 mfma16(bf16x8 a, bf16x8 b, f32x4 c) {
  return __builtin_amdgcn_mfma_f32_16x16x32_bf16(a, b, c, 0, 0, 0);
}

__device__ __forceinline__ f32x16 mfma32(bf16x8 a, bf16x8 b, f32x16 c) {
  return __builtin_amdgcn_mfma_f32_32x32x16_bf16(a, b, c, 0, 0, 0);
}

__device__ __forceinline__ u32 cvtpk(float lo, float hi) {
  u32 r;
  asm("v_cvt_pk_bf16_f32 %0, %1, %2" : "=v"(r) : "v"(lo), "v"(hi));
  return r;
}

__device__ __forceinline__ f32x16 zero16() {
  f32x16 z;
  #pragma unroll
  for (int i = 0; i < 16; ++i) z[i] = 0.f;
  return z;
}

// ---------------- Kernel 1: x [B][C][N] f32 -> Xt [B][N][C] bf16 ----------------
__global__ __launch_bounds__(256) void k_transpose(const float* __restrict__ x,
                                                   u16* __restrict__ xt) {
  __shared__ float tile[32][33];
  const int b = blockIdx.z;
  const int n0 = blockIdx.x * 32;
  const int c0 = blockIdx.y * 32;
  const int tj = threadIdx.x & 31;
  const int ti = threadIdx.x >> 5;
  const float* xb = x + (size_t)b * CC * NN;
  #pragma unroll
  for (int i = ti; i < 32; i += 8)
    tile[i][tj] = xb[(size_t)(c0 + i) * NN + (n0 + tj)];
  __syncthreads();
  u16* xtb = xt + (size_t)b * NN * CC;
  #pragma unroll
  for (int i = ti; i < 32; i += 8)
    xtb[(size_t)(n0 + i) * CC + (c0 + tj)] = f2bf(tile[tj][i]);
}

// ------------- Kernel 2: Q,K projection -> Q,K [B][N][64] bf16 -------------
__global__ __launch_bounds__(512) void k_proj_qk(
    const u16* __restrict__ xt, const float* __restrict__ Wq, const float* __restrict__ bq,
    const float* __restrict__ Wk, const float* __restrict__ bk,
    u16* __restrict__ Qo, u16* __restrict__ Ko) {
  __shared__ __align__(16) u16 wl[128 * 64];
  const int b = blockIdx.y;
  const int n0 = blockIdx.x * 64;
  const int t = threadIdx.x;
  const int w = t >> 6, l = t & 63, g = l >> 4, l15 = l & 15;
  const int rw = w & 3, ch = w >> 2;
  f32x4 acc[4];
  #pragma unroll
  for (int i = 0; i < 4; ++i) acc[i] = f32x4{0.f, 0.f, 0.f, 0.f};
  const u16* xrow = xt + (size_t)(b * NN + n0 + rw * 16 + l15) * CC;

  for (int kt = 0; kt < 8; ++kt) {
    #pragma unroll
    for (int i = 0; i < 16; ++i) {
      int e = i * 512 + t;
      int o = e >> 6, cc = e & 63;
      float wv = (o < 64) ? Wq[(size_t)o * CC + kt * 64 + cc]
                          : Wk[(size_t)(o - 64) * CC + kt * 64 + cc];
      wl[o * 64 + ((((cc >> 3) ^ (o & 7)) << 3) | (cc & 7))] = f2bf(wv);
    }
    __syncthreads();
    #pragma unroll
    for (int ks = 0; ks < 2; ++ks) {
      bf16x8 a = ld_bf8(xrow + kt * 64 + ks * 32 + g * 8);
      #pragma unroll
      for (int cf = 0; cf < 4; ++cf) {
        int o = (ch * 4 + cf) * 16 + l15;
        bf16x8 bb = ld_bf8(&wl[o * 64 + (((ks * 4 + g) ^ (o & 7)) << 3)]);
        acc[cf] = mfma16(a, bb, acc[cf]);
      }
    }
    __syncthreads();
  }
  #pragma unroll
  for (int cf = 0; cf < 4; ++cf) {
    int o = (ch * 4 + cf) * 16 + l15;
    float bias = (o < 64) ? bq[o] : bk[o - 64];
    #pragma unroll
    for (int r = 0; r < 4; ++r) {
      int n = n0 + rw * 16 + g * 4 + r;
      u16 val = f2bf(acc[cf][r] + bias);
      if (o < 64) Qo[(size_t)(b * NN + n) * DQd + o] = val;
      else        Ko[(size_t)(b * NN + n) * DQd + (o - 64)] = val;
    }
  }
}

// ------------- Kernel 3: V projection -> Vt [B][512][N] bf16 (transposed) -------------
__global__ __launch_bounds__(256) void k_proj_v(
    const u16* __restrict__ xt, const float* __restrict__ Wv, const float* __restrict__ bv,
    u16* __restrict__ Vt) {
  __shared__ __align__(16) u16 wl[128 * 64];
  const int b = blockIdx.z;
  const int co0 = blockIdx.y * 128;
  const int n0 = blockIdx.x * 128;
  const int t = threadIdx.x;
  const int w = t >> 6, l = t & 63, g = l >> 4, l15 = l & 15;
  f32x4 acc[2][8];
  #pragma unroll
  for (int i = 0; i < 2; ++i)
    #pragma unroll
    for (int j = 0; j < 8; ++j) acc[i][j] = f32x4{0.f, 0.f, 0.f, 0.f};

  for (int kt = 0; kt < 8; ++kt) {
    #pragma unroll
    for (int i = 0; i < 32; ++i) {
      int e = i * 256 + t;
      int o = e >> 6, cc = e & 63;
      float wv = Wv[(size_t)(co0 + o) * CC + kt * 64 + cc];
      wl[o * 64 + ((((cc >> 3) ^ (o & 7)) << 3) | (cc & 7))] = f2bf(wv);
    }
    __syncthreads();
    #pragma unroll
    for (int ks = 0; ks < 2; ++ks) {
      int o0 = w * 32 + l15, o1 = w * 32 + 16 + l15;
      bf16x8 a0 = ld_bf8(&wl[o0 * 64 + (((ks * 4 + g) ^ (o0 & 7)) << 3)]);
      bf16x8 a1 = ld_bf8(&wl[o1 * 64 + (((ks * 4 + g) ^ (o1 & 7)) << 3)]);
      #pragma unroll
      for (int cf = 0; cf < 8; ++cf) {
        const u16* bp = xt + (size_t)(b * NN + n0 + cf * 16 + l15) * CC + kt * 64 + ks * 32 + g * 8;
        bf16x8 bb = ld_bf8(bp);
        acc[0][cf] = mfma16(a0, bb, acc[0][cf]);
        acc[1][cf] = mfma16(a1, bb, acc[1][cf]);
      }
    }
    __syncthreads();
  }
  #pragma unroll
  for (int rf = 0; rf < 2; ++rf) {
    #pragma unroll
    for (int r = 0; r < 4; ++r) {
      int c = co0 + w * 32 + rf * 16 + g * 4 + r;
      float bias = bv[c];
      #pragma unroll
      for (int cf = 0; cf < 8; ++cf) {
        int n = n0 + cf * 16 + l15;
        Vt[(size_t)(b * CC + c) * NN + n] = f2bf(acc[rf][cf][r] + bias);
      }
    }
  }
}

// ------------- Kernel 4: flash attention (swapped-QK^T, in-register softmax) -------------
// Grid 256 (XCD-chunked swizzle), block 512 thr (8 waves).
// Block: 256 q-rows (wave w -> q [qw, qw+32)), ch-slice 128. KVBLK=64.
// S^T = mfma32(K, Q): lane (h,cl) holds S[kv-rows][q=qw+cl] in regs
//   (kv = (reg&3)+8*(reg>>2)+4h per measured D-layout); softmax fully in-register.
// P-frags (A-operand, mapping k = 8h+e) built via cvt_pk + shfl_xor(32) half-exchange:
//   lane half h natively holds kv {4h..4h+3, 8+4h..8+4h+3} per 16-slice; exchange
//   E=shfl_xor(h?Z:W) then select -> {h?E:Z, h?W:E} gives exact 8h+e order.
// V LDS double-buffered [kc8][chl^kc8][8], reg-staged issue-early/write-late.
// 1 barrier per KV tile.
__global__ __launch_bounds__(512, 2) void k_attn(
    const u16* __restrict__ Q, const u16* __restrict__ K, const u16* __restrict__ Vt,
    const float* __restrict__ x, const float* __restrict__ gamma,
    float* __restrict__ out) {
  __shared__ __align__(16) u16 v_lds[2][8192];  // [kc8(8)][chl^kc8 (128)][8 kv-elems]
  const int bid = blockIdx.x;
  const int oid = (bid & 7) * 32 + (bid >> 3);  // bijective XCD chunking (nwg=256)
  const int qi = oid & 15, ci = (oid >> 4) & 3, b = oid >> 6;
  const int q0 = qi * 256, ch0 = ci * 128;
  const int tid = threadIdx.x;
  const int w = tid >> 6, lane = tid & 63;
  const int h = lane >> 5, cl = lane & 31;
  const int qw = q0 + w * 32;

  // Q fragments (B-operand: col=q=cl, k = 8h+e per 16-slice)
  const u16* qp = Q + (size_t)(b * NN + qw + cl) * DQd + h * 8;
  const bf16x8 qf0 = ld_bf8(qp);
  const bf16x8 qf1 = ld_bf8(qp + 16);
  const bf16x8 qf2 = ld_bf8(qp + 32);
  const bf16x8 qf3 = ld_bf8(qp + 48);

  // K pointers + preload tile 0 into kb[0]
  const u16* kp0 = K + (size_t)(b * NN + cl) * DQd + h * 8;
  const u16* kp1 = kp0 + 32 * DQd;
  bf16x8 kb[2][8];
  kb[0][0] = ld_bf8(kp0);      kb[0][1] = ld_bf8(kp0 + 16);
  kb[0][2] = ld_bf8(kp0 + 32); kb[0][3] = ld_bf8(kp0 + 48);
  kb[0][4] = ld_bf8(kp1);      kb[0][5] = ld_bf8(kp1 + 16);
  kb[0][6] = ld_bf8(kp1 + 32); kb[0][7] = ld_bf8(kp1 + 48);
  kp0 += 64 * DQd; kp1 += 64 * DQd;

  // V stage pointers; stage tile 0 -> buf 0
  const u16* vs0 = Vt + (size_t)(b * CC + ch0 + (tid >> 3)) * NN + (tid & 7) * 8;
  const u16* vs1 = vs0 + (size_t)64 * NN;
  const int wr0 = ((tid & 7) * 128 + ((tid >> 3) ^ (tid & 7))) * 8;
  {
    uint4 a0 = *(const uint4*)vs0;
    uint4 a1 = *(const uint4*)vs1;
    *(uint4*)&v_lds[0][wr0] = a0;
    *(uint4*)&v_lds[0][wr0 + 512] = a1;
    vs0 += 64; vs1 += 64;
  }

  // V read offsets per lane: kc8 = 2*kap + h; slot(c) = c ^ kc8 (low 3 bits)
  const int ek0 = (2 * 0 + h) * 1024 + ((cl ^ (2 * 0 + h)) * 8);
  const int ek1 = (2 * 1 + h) * 1024 + ((cl ^ (2 * 1 + h)) * 8);
  const int ek2 = (2 * 2 + h) * 1024 + ((cl ^ (2 * 2 + h)) * 8);
  const int ek3 = (2 * 3 + h) * 1024 + ((cl ^ (2 * 3 + h)) * 8);

  f32x16 acc[4];
  #pragma unroll
  for (int i = 0; i < 4; ++i) acc[i] = zero16();
  float m_run = -1e30f, l_run = 0.f;

#define PACKF(parr, c, dst)                                                    \
  {                                                                            \
    u32 Z0 = cvtpk(parr[8 * (c) + 0], parr[8 * (c) + 1]);                      \
    u32 Z1 = cvtpk(parr[8 * (c) + 2], parr[8 * (c) + 3]);                      \
    u32 W0 = cvtpk(parr[8 * (c) + 4], parr[8 * (c) + 5]);                      \
    u32 W1 = cvtpk(parr[8 * (c) + 6], parr[8 * (c) + 7]);                      \
    u32 E0 = (u32)__shfl_xor((int)(h ? Z0 : W0), 32);                          \
    u32 E1 = (u32)__shfl_xor((int)(h ? Z1 : W1), 32);                          \
    union { u32 u[4]; bf16x8 v; } uu;                                          \
    uu.u[0] = h ? E0 : Z0;                                                     \
    uu.u[1] = h ? E1 : Z1;                                                     \
    uu.u[2] = h ? W0 : E0;                                                     \
    uu.u[3] = h ? W1 : E1;                                                     \
    dst = uu.v;                                                                \
  }

#define ATTN_TILE(t, CUR, NXT)                                                 \
  {                                                                            \
    __syncthreads();                                                           \
    const bool pre = (t) < 63;                                                 \
    uint4 sa0, sa1;                                                            \
    if (pre) {                                                                 \
      sa0 = *(const uint4*)vs0;                                                \
      sa1 = *(const uint4*)vs1;                                                \
      kb[NXT][0] = ld_bf8(kp0);      kb[NXT][1] = ld_bf8(kp0 + 16);            \
      kb[NXT][2] = ld_bf8(kp0 + 32); kb[NXT][3] = ld_bf8(kp0 + 48);            \
      kb[NXT][4] = ld_bf8(kp1);      kb[NXT][5] = ld_bf8(kp1 + 16);            \
      kb[NXT][6] = ld_bf8(kp1 + 32); kb[NXT][7] = ld_bf8(kp1 + 48);            \
      vs0 += 64; vs1 += 64; kp0 += 64 * DQd; kp1 += 64 * DQd;                  \
    }                                                                          \
    f32x16 s0 = zero16(), s1 = zero16();                                       \
    s0 = mfma32(kb[CUR][0], qf0, s0);                                          \
    s0 = mfma32(kb[CUR][1], qf1, s0);                                          \
    s0 = mfma32(kb[CUR][2], qf2, s0);                                          \
    s0 = mfma32(kb[CUR][3], qf3, s0);                                          \
    s1 = mfma32(kb[CUR][4], qf0, s1);                                          \
    s1 = mfma32(kb[CUR][5], qf1, s1);                                          \
    s1 = mfma32(kb[CUR][6], qf2, s1);                                          \
    s1 = mfma32(kb[CUR][7], qf3, s1);                                          \
    float mt[8];                                                               \
    _Pragma("unroll")                                                          \
    for (int i = 0; i < 8; ++i)                                                \
      mt[i] = fmaxf(fmaxf(s0[i], s0[i + 8]), fmaxf(s1[i], s1[i + 8]));         \
    _Pragma("unroll")                                                          \
    for (int i = 0; i < 4; ++i) mt[i] = fmaxf(mt[i], mt[i + 4]);               \
    float mx = fmaxf(fmaxf(mt[0], mt[2]), fmaxf(mt[1], mt[3]));                \
    mx = fmaxf(mx, __shfl_xor(mx, 32));                                        \
    if (!__all(mx - m_run <= 8.0f)) {                                          \
      float m_new = fmaxf(m_run, mx);                                          \
      float alv = __expf(m_run - m_new);                                       \
      m_run = m_new;                                                           \
      float A0[4], A1[4], A2[4], A3[4];                                        \
      _Pragma("unroll")                                                        \
      for (int r = 0; r < 4; ++r) {                                            \
        A0[r] = __shfl(alv, 4 * h + r);                                        \
        A1[r] = __shfl(alv, 8 + 4 * h + r);                                    \
        A2[r] = __shfl(alv, 16 + 4 * h + r);                                   \
        A3[r] = __shfl(alv, 24 + 4 * h + r);                                   \
      }                                                                        \
      _Pragma("unroll")                                                        \
      for (int c_ = 0; c_ < 4; ++c_) {                                         \
        _Pragma("unroll")                                                      \
        for (int r = 0; r < 4; ++r) {                                          \
          acc[c_][0 + r] *= A0[r];                                             \
          acc[c_][4 + r] *= A1[r];                                             \
          acc[c_][8 + r] *= A2[r];                                             \
          acc[c_][12 + r] *= A3[r];                                            \
        }                                                                      \
      }                                                                        \
      l_run *= alv;                                                            \
    }                                                                          \
    float p0[16], p1[16];                                                      \
    _Pragma("unroll")                                                          \
    for (int i = 0; i < 16; ++i) {                                             \
      p0[i] = __expf(s0[i] - m_run);                                           \
      p1[i] = __expf(s1[i] - m_run);                                           \
    }                                                                          \
    float st[8];                                                               \
    _Pragma("unroll")                                                          \
    for (int i = 0; i < 8; ++i)                                                \
      st[i] = (p0[i] + p0[i + 8]) + (p1[i] + p1[i + 8]);                       \
    _Pragma("unroll")                                                          \
    for (int i = 0; i < 4; ++i) st[i] += st[i + 4];                            \
    float ps = (st[0] + st[2]) + (st[1] + st[3]);                              \
    ps += __shfl_xor(ps, 32);                                                  \
    l_run += ps;                                                               \
    bf16x8 pf0, pf1, pf2, pf3;                                                 \
    PACKF(p0, 0, pf0);                                                         \
    PACKF(p0, 1, pf1);                                                         \
    PACKF(p1, 0, pf2);                                                         \
    PACKF(p1, 1, pf3);                                                         \
    _Pragma("unroll")                                                          \
    for (int cht = 0; cht < 4; ++cht) {                                        \
      bf16x8 vf0 = *(const bf16x8*)&v_lds[CUR][ek0 + cht * 256];               \
      bf16x8 vf1 = *(const bf16x8*)&v_lds[CUR][ek1 + cht * 256];               \
      bf16x8 vf2 = *(const bf16x8*)&v_lds[CUR][ek2 + cht * 256];               \
      bf16x8 vf3 = *(const bf16x8*)&v_lds[CUR][ek3 + cht * 256];               \
      acc[cht] = mfma32(pf0, vf0, acc[cht]);                                   \
      acc[cht] = mfma32(pf1, vf1, acc[cht]);                                   \
      acc[cht] = mfma32(pf2, vf2, acc[cht]);                                   \
      acc[cht] = mfma32(pf3, vf3, acc[cht]);                                   \
    }                                                                          \
    if (pre) {                                                                 \
      *(uint4*)&v_lds[NXT][wr0] = sa0;                                         \
      *(uint4*)&v_lds[NXT][wr0 + 512] = sa1;                                   \
    }                                                                          \
  }

  #pragma unroll 1
  for (int tt = 0; tt < 32; ++tt) {
    ATTN_TILE(2 * tt, 0, 1);
    ATTN_TILE(2 * tt + 1, 1, 0);
  }

  // epilogue: normalize, gamma, residual
  const float inv_l = 1.f / l_run;
  f32x4 Iv[4];
  #pragma unroll
  for (int r = 0; r < 4; ++r) {
    Iv[0][r] = __shfl(inv_l, 4 * h + r);
    Iv[1][r] = __shfl(inv_l, 8 + 4 * h + r);
    Iv[2][r] = __shfl(inv_l, 16 + 4 * h + r);
    Iv[3][r] = __shfl(inv_l, 24 + 4 * h + r);
  }
  const float gm = gamma[0];
  #pragma unroll
  for (int cht = 0; cht < 4; ++cht) {
    const int ch = ch0 + cht * 32 + cl;
    const size_t rb = (size_t)(b * CC + ch) * NN + qw;
    #pragma unroll
    for (int j = 0; j < 4; ++j) {
      const size_t o = rb + 8 * j + 4 * h;
      f32x4 xv = *(const f32x4*)&x[o];
      f32x4 ov;
      #pragma unroll
      for (int r = 0; r < 4; ++r)
        ov[r] = gm * (acc[cht][4 * j + r] * Iv[j][r]) + xv[r];
      *(f32x4*)&out[o] = ov;
    }
  }
#undef ATTN_TILE
#undef PACKF
}

extern "C" void kernel_launch(void* const* d_in, const int* in_sizes, int n_in,
                              void* d_out, int out_size, void* d_ws, size_t ws_size,
                              hipStream_t stream) {
  (void)in_sizes; (void)n_in; (void)out_size; (void)ws_size;
  const float* x  = (const float*)d_in[0];
  const float* Wq = (const float*)d_in[1];
  const float* bq = (const float*)d_in[2];
  const float* Wk = (const float*)d_in[3];
  const float* bk = (const float*)d_in[4];
  const float* Wv = (const float*)d_in[5];
  const float* bv = (const float*)d_in[6];
  const float* gm = (const float*)d_in[7];
  float* out = (float*)d_out;

  char* ws = (char*)d_ws;
  u16* Xt = (u16*)ws;                                   // 16 MB
  u16* Qw = (u16*)(ws + (size_t)16 * 1024 * 1024);      //  2 MB
  u16* Kw = (u16*)(ws + (size_t)18 * 1024 * 1024);      //  2 MB
  u16* Vt = (u16*)(ws + (size_t)20 * 1024 * 1024);      // 16 MB

  k_transpose<<<dim3(NN / 32, CC / 32, BB), 256, 0, stream>>>(x, Xt);
  k_proj_qk<<<dim3(NN / 64, BB), 512, 0, stream>>>(Xt, Wq, bq, Wk, bk, Qw, Kw);
  k_proj_v<<<dim3(NN / 128, CC / 128, BB), 256, 0, stream>>>(Xt, Wv, bv, Vt);
  k_attn<<<dim3(256), 512, 0, stream>>>(Qw, Kw, Vt, x, gm, out);
}

// Round 6
// 326.914 us; speedup vs baseline: 1.0007x; 1.0007x over previous
//
#include <hip/hip_runtime.h>
#include <stdint.h>

#define BB 4
#define CC 512
#define NN 4096
#define DQd 64

typedef unsigned short u16;
typedef unsigned int u32;
typedef __bf16 bf16x8 __attribute__((ext_vector_type(8)));
typedef float f32x4 __attribute__((ext_vector_type(4)));
typedef float f32x16 __attribute__((ext_vector_type(16)));

__device__ __forceinline__ u16 f2bf(float f) {
  union { float f; u32 u; } v; v.f = f;
  u32 r = v.u + 0x7FFFu + ((v.u >> 16) & 1u);
  return (u16)(r >> 16);
}

__device__ __forceinline__ bf16x8 ld_bf8(const u16* p) {
  return *reinterpret_cast<const bf16x8*>(p);
}

__device__ __forceinline__ f32x4 mfma16(bf16x8 a, bf16x8 b, f32x4 c) {
  return __builtin_amdgcn_mfma_f32_16x16x32_bf16(a, b, c, 0, 0, 0);
}

__device__ __forceinline__ f32x16 mfma32(bf16x8 a, bf16x8 b, f32x16 c) {
  return __builtin_amdgcn_mfma_f32_32x32x16_bf16(a, b, c, 0, 0, 0);
}

__device__ __forceinline__ u32 cvtpk(float lo, float hi) {
  u32 r;
  asm("v_cvt_pk_bf16_f32 %0, %1, %2" : "=v"(r) : "v"(lo), "v"(hi));
  return r;
}

__device__ __forceinline__ f32x16 zero16() {
  f32x16 z;
  #pragma unroll
  for (int i = 0; i < 16; ++i) z[i] = 0.f;
  return z;
}

// ---------------- Kernel 1: x [B][C][N] f32 -> Xt [B][N][C] bf16 ----------------
__global__ __launch_bounds__(256) void k_transpose(const float* __restrict__ x,
                                                   u16* __restrict__ xt) {
  __shared__ float tile[32][33];
  const int b = blockIdx.z;
  const int n0 = blockIdx.x * 32;
  const int c0 = blockIdx.y * 32;
  const int tj = threadIdx.x & 31;
  const int ti = threadIdx.x >> 5;
  const float* xb = x + (size_t)b * CC * NN;
  #pragma unroll
  for (int i = ti; i < 32; i += 8)
    tile[i][tj] = xb[(size_t)(c0 + i) * NN + (n0 + tj)];
  __syncthreads();
  u16* xtb = xt + (size_t)b * NN * CC;
  #pragma unroll
  for (int i = ti; i < 32; i += 8)
    xtb[(size_t)(n0 + i) * CC + (c0 + tj)] = f2bf(tile[tj][i]);
}

// ------------- Kernel 2: Q,K projection -> Q,K [B][N][64] bf16 -------------
__global__ __launch_bounds__(512) void k_proj_qk(
    const u16* __restrict__ xt, const float* __restrict__ Wq, const float* __restrict__ bq,
    const float* __restrict__ Wk, const float* __restrict__ bk,
    u16* __restrict__ Qo, u16* __restrict__ Ko) {
  __shared__ __align__(16) u16 wl[128 * 64];
  const int b = blockIdx.y;
  const int n0 = blockIdx.x * 64;
  const int t = threadIdx.x;
  const int w = t >> 6, l = t & 63, g = l >> 4, l15 = l & 15;
  const int rw = w & 3, ch = w >> 2;
  f32x4 acc[4];
  #pragma unroll
  for (int i = 0; i < 4; ++i) acc[i] = f32x4{0.f, 0.f, 0.f, 0.f};
  const u16* xrow = xt + (size_t)(b * NN + n0 + rw * 16 + l15) * CC;

  for (int kt = 0; kt < 8; ++kt) {
    #pragma unroll
    for (int i = 0; i < 16; ++i) {
      int e = i * 512 + t;
      int o = e >> 6, cc = e & 63;
      float wv = (o < 64) ? Wq[(size_t)o * CC + kt * 64 + cc]
                          : Wk[(size_t)(o - 64) * CC + kt * 64 + cc];
      wl[o * 64 + ((((cc >> 3) ^ (o & 7)) << 3) | (cc & 7))] = f2bf(wv);
    }
    __syncthreads();
    #pragma unroll
    for (int ks = 0; ks < 2; ++ks) {
      bf16x8 a = ld_bf8(xrow + kt * 64 + ks * 32 + g * 8);
      #pragma unroll
      for (int cf = 0; cf < 4; ++cf) {
        int o = (ch * 4 + cf) * 16 + l15;
        bf16x8 bb = ld_bf8(&wl[o * 64 + (((ks * 4 + g) ^ (o & 7)) << 3)]);
        acc[cf] = mfma16(a, bb, acc[cf]);
      }
    }
    __syncthreads();
  }
  #pragma unroll
  for (int cf = 0; cf < 4; ++cf) {
    int o = (ch * 4 + cf) * 16 + l15;
    float bias = (o < 64) ? bq[o] : bk[o - 64];
    #pragma unroll
    for (int r = 0; r < 4; ++r) {
      int n = n0 + rw * 16 + g * 4 + r;
      u16 val = f2bf(acc[cf][r] + bias);
      if (o < 64) Qo[(size_t)(b * NN + n) * DQd + o] = val;
      else        Ko[(size_t)(b * NN + n) * DQd + (o - 64)] = val;
    }
  }
}

// ------------- Kernel 3: V projection -> Vt [B][512][N] bf16 (transposed) -------------
__global__ __launch_bounds__(256) void k_proj_v(
    const u16* __restrict__ xt, const float* __restrict__ Wv, const float* __restrict__ bv,
    u16* __restrict__ Vt) {
  __shared__ __align__(16) u16 wl[128 * 64];
  const int b = blockIdx.z;
  const int co0 = blockIdx.y * 128;
  const int n0 = blockIdx.x * 128;
  const int t = threadIdx.x;
  const int w = t >> 6, l = t & 63, g = l >> 4, l15 = l & 15;
  f32x4 acc[2][8];
  #pragma unroll
  for (int i = 0; i < 2; ++i)
    #pragma unroll
    for (int j = 0; j < 8; ++j) acc[i][j] = f32x4{0.f, 0.f, 0.f, 0.f};

  for (int kt = 0; kt < 8; ++kt) {
    #pragma unroll
    for (int i = 0; i < 32; ++i) {
      int e = i * 256 + t;
      int o = e >> 6, cc = e & 63;
      float wv = Wv[(size_t)(co0 + o) * CC + kt * 64 + cc];
      wl[o * 64 + ((((cc >> 3) ^ (o & 7)) << 3) | (cc & 7))] = f2bf(wv);
    }
    __syncthreads();
    #pragma unroll
    for (int ks = 0; ks < 2; ++ks) {
      int o0 = w * 32 + l15, o1 = w * 32 + 16 + l15;
      bf16x8 a0 = ld_bf8(&wl[o0 * 64 + (((ks * 4 + g) ^ (o0 & 7)) << 3)]);
      bf16x8 a1 = ld_bf8(&wl[o1 * 64 + (((ks * 4 + g) ^ (o1 & 7)) << 3)]);
      #pragma unroll
      for (int cf = 0; cf < 8; ++cf) {
        const u16* bp = xt + (size_t)(b * NN + n0 + cf * 16 + l15) * CC + kt * 64 + ks * 32 + g * 8;
        bf16x8 bb = ld_bf8(bp);
        acc[0][cf] = mfma16(a0, bb, acc[0][cf]);
        acc[1][cf] = mfma16(a1, bb, acc[1][cf]);
      }
    }
    __syncthreads();
  }
  #pragma unroll
  for (int rf = 0; rf < 2; ++rf) {
    #pragma unroll
    for (int r = 0; r < 4; ++r) {
      int c = co0 + w * 32 + rf * 16 + g * 4 + r;
      float bias = bv[c];
      #pragma unroll
      for (int cf = 0; cf < 8; ++cf) {
        int n = n0 + cf * 16 + l15;
        Vt[(size_t)(b * CC + c) * NN + n] = f2bf(acc[rf][cf][r] + bias);
      }
    }
  }
}

// ------------- Kernel 4: flash attention (swapped-QK^T, in-register softmax) -------------
// Grid 256 (XCD-chunked swizzle), block 512 thr (8 waves).
// Block: 256 q-rows (wave w -> q [qw, qw+32)), ch-slice 128. KVBLK=64.
// S^T = mfma32(K, Q): lane (h,cl) holds S[kv-rows][q=qw+cl] in regs;
// softmax fully in-register; P-frags via cvt_pk + shfl_xor(32) half-exchange.
// V LDS double-buffered [kc8][chl^kc8][8], reg-staged; K reg double-buffered.
// 1 barrier per KV tile.
// launch_bounds (512,1): live set ~210 VGPR; min-blocks=2 capped at 128 and
// forced spills (round-5: VGPR_Count=128, 222us). Grid=1 block/CU anyway.
__global__ __launch_bounds__(512, 1) void k_attn(
    const u16* __restrict__ Q, const u16* __restrict__ K, const u16* __restrict__ Vt,
    const float* __restrict__ x, const float* __restrict__ gamma,
    float* __restrict__ out) {
  __shared__ __align__(16) u16 v_lds[2][8192];  // [kc8(8)][chl^kc8 (128)][8 kv-elems]
  const int bid = blockIdx.x;
  const int oid = (bid & 7) * 32 + (bid >> 3);  // bijective XCD chunking (nwg=256)
  const int qi = oid & 15, ci = (oid >> 4) & 3, b = oid >> 6;
  const int q0 = qi * 256, ch0 = ci * 128;
  const int tid = threadIdx.x;
  const int w = tid >> 6, lane = tid & 63;
  const int h = lane >> 5, cl = lane & 31;
  const int qw = q0 + w * 32;

  // Q fragments (B-operand: col=q=cl, k = 8h+e per 16-slice)
  const u16* qp = Q + (size_t)(b * NN + qw + cl) * DQd + h * 8;
  const bf16x8 qf0 = ld_bf8(qp);
  const bf16x8 qf1 = ld_bf8(qp + 16);
  const bf16x8 qf2 = ld_bf8(qp + 32);
  const bf16x8 qf3 = ld_bf8(qp + 48);

  // K pointers + preload tile 0 into kb[0]
  const u16* kp0 = K + (size_t)(b * NN + cl) * DQd + h * 8;
  const u16* kp1 = kp0 + 32 * DQd;
  bf16x8 kb[2][8];
  kb[0][0] = ld_bf8(kp0);      kb[0][1] = ld_bf8(kp0 + 16);
  kb[0][2] = ld_bf8(kp0 + 32); kb[0][3] = ld_bf8(kp0 + 48);
  kb[0][4] = ld_bf8(kp1);      kb[0][5] = ld_bf8(kp1 + 16);
  kb[0][6] = ld_bf8(kp1 + 32); kb[0][7] = ld_bf8(kp1 + 48);
  kp0 += 64 * DQd; kp1 += 64 * DQd;

  // V stage pointers; stage tile 0 -> buf 0
  const u16* vs0 = Vt + (size_t)(b * CC + ch0 + (tid >> 3)) * NN + (tid & 7) * 8;
  const u16* vs1 = vs0 + (size_t)64 * NN;
  const int wr0 = ((tid & 7) * 128 + ((tid >> 3) ^ (tid & 7))) * 8;
  {
    uint4 a0 = *(const uint4*)vs0;
    uint4 a1 = *(const uint4*)vs1;
    *(uint4*)&v_lds[0][wr0] = a0;
    *(uint4*)&v_lds[0][wr0 + 512] = a1;
    vs0 += 64; vs1 += 64;
  }

  // V read offsets per lane: kc8 = 2*kap + h; slot(c) = c ^ kc8 (low 3 bits)
  const int ek0 = (2 * 0 + h) * 1024 + ((cl ^ (2 * 0 + h)) * 8);
  const int ek1 = (2 * 1 + h) * 1024 + ((cl ^ (2 * 1 + h)) * 8);
  const int ek2 = (2 * 2 + h) * 1024 + ((cl ^ (2 * 2 + h)) * 8);
  const int ek3 = (2 * 3 + h) * 1024 + ((cl ^ (2 * 3 + h)) * 8);

  f32x16 acc[4];
  #pragma unroll
  for (int i = 0; i < 4; ++i) acc[i] = zero16();
  float m_run = -1e30f, l_run = 0.f;

#define PACKF(parr, c, dst)                                                    \
  {                                                                            \
    u32 Z0 = cvtpk(parr[8 * (c) + 0], parr[8 * (c) + 1]);                      \
    u32 Z1 = cvtpk(parr[8 * (c) + 2], parr[8 * (c) + 3]);                      \
    u32 W0 = cvtpk(parr[8 * (c) + 4], parr[8 * (c) + 5]);                      \
    u32 W1 = cvtpk(parr[8 * (c) + 6], parr[8 * (c) + 7]);                      \
    u32 E0 = (u32)__shfl_xor((int)(h ? Z0 : W0), 32);                          \
    u32 E1 = (u32)__shfl_xor((int)(h ? Z1 : W1), 32);                          \
    union { u32 u[4]; bf16x8 v; } uu;                                          \
    uu.u[0] = h ? E0 : Z0;                                                     \
    uu.u[1] = h ? E1 : Z1;                                                     \
    uu.u[2] = h ? W0 : E0;                                                     \
    uu.u[3] = h ? W1 : E1;                                                     \
    dst = uu.v;                                                                \
  }

#define ATTN_TILE(t, CUR, NXT)                                                 \
  {                                                                            \
    __syncthreads();                                                           \
    const bool pre = (t) < 63;                                                 \
    uint4 sa0, sa1;                                                            \
    if (pre) {                                                                 \
      sa0 = *(const uint4*)vs0;                                                \
      sa1 = *(const uint4*)vs1;                                                \
      kb[NXT][0] = ld_bf8(kp0);      kb[NXT][1] = ld_bf8(kp0 + 16);            \
      kb[NXT][2] = ld_bf8(kp0 + 32); kb[NXT][3] = ld_bf8(kp0 + 48);            \
      kb[NXT][4] = ld_bf8(kp1);      kb[NXT][5] = ld_bf8(kp1 + 16);            \
      kb[NXT][6] = ld_bf8(kp1 + 32); kb[NXT][7] = ld_bf8(kp1 + 48);            \
      vs0 += 64; vs1 += 64; kp0 += 64 * DQd; kp1 += 64 * DQd;                  \
    }                                                                          \
    f32x16 s0 = zero16(), s1 = zero16();                                       \
    s0 = mfma32(kb[CUR][0], qf0, s0);                                          \
    s0 = mfma32(kb[CUR][1], qf1, s0);                                          \
    s0 = mfma32(kb[CUR][2], qf2, s0);                                          \
    s0 = mfma32(kb[CUR][3], qf3, s0);                                          \
    s1 = mfma32(kb[CUR][4], qf0, s1);                                          \
    s1 = mfma32(kb[CUR][5], qf1, s1);                                          \
    s1 = mfma32(kb[CUR][6], qf2, s1);                                          \
    s1 = mfma32(kb[CUR][7], qf3, s1);                                          \
    float mt[8];                                                               \
    _Pragma("unroll")                                                          \
    for (int i = 0; i < 8; ++i)                                                \
      mt[i] = fmaxf(fmaxf(s0[i], s0[i + 8]), fmaxf(s1[i], s1[i + 8]));         \
    _Pragma("unroll")                                                          \
    for (int i = 0; i < 4; ++i) mt[i] = fmaxf(mt[i], mt[i + 4]);               \
    float mx = fmaxf(fmaxf(mt[0], mt[2]), fmaxf(mt[1], mt[3]));                \
    mx = fmaxf(mx, __shfl_xor(mx, 32));                                        \
    if (!__all(mx - m_run <= 8.0f)) {                                          \
      float m_new = fmaxf(m_run, mx);                                          \
      float alv = __expf(m_run - m_new);                                       \
      m_run = m_new;                                                           \
      float A0[4], A1[4], A2[4], A3[4];                                        \
      _Pragma("unroll")                                                        \
      for (int r = 0; r < 4; ++r) {                                            \
        A0[r] = __shfl(alv, 4 * h + r);                                        \
        A1[r] = __shfl(alv, 8 + 4 * h + r);                                    \
        A2[r] = __shfl(alv, 16 + 4 * h + r);                                   \
        A3[r] = __shfl(alv, 24 + 4 * h + r);                                   \
      }                                                                        \
      _Pragma("unroll")                                                        \
      for (int c_ = 0; c_ < 4; ++c_) {                                         \
        _Pragma("unroll")                                                      \
        for (int r = 0; r < 4; ++r) {                                          \
          acc[c_][0 + r] *= A0[r];                                             \
          acc[c_][4 + r] *= A1[r];                                             \
          acc[c_][8 + r] *= A2[r];                                             \
          acc[c_][12 + r] *= A3[r];                                            \
        }                                                                      \
      }                                                                        \
      l_run *= alv;                                                            \
    }                                                                          \
    float p0[16], p1[16];                                                      \
    _Pragma("unroll")                                                          \
    for (int i = 0; i < 16; ++i) {                                             \
      p0[i] = __expf(s0[i] - m_run);                                           \
      p1[i] = __expf(s1[i] - m_run);                                           \
    }                                                                          \
    float st[8];                                                               \
    _Pragma("unroll")                                                          \
    for (int i = 0; i < 8; ++i)                                                \
      st[i] = (p0[i] + p0[i + 8]) + (p1[i] + p1[i + 8]);                       \
    _Pragma("unroll")                                                          \
    for (int i = 0; i < 4; ++i) st[i] += st[i + 4];                            \
    float ps = (st[0] + st[2]) + (st[1] + st[3]);                              \
    ps += __shfl_xor(ps, 32);                                                  \
    l_run += ps;                                                               \
    bf16x8 pf0, pf1, pf2, pf3;                                                 \
    PACKF(p0, 0, pf0);                                                         \
    PACKF(p0, 1, pf1);                                                         \
    PACKF(p1, 0, pf2);                                                         \
    PACKF(p1, 1, pf3);                                                         \
    _Pragma("unroll")                                                          \
    for (int cht = 0; cht < 4; ++cht) {                                        \
      bf16x8 vf0 = *(const bf16x8*)&v_lds[CUR][ek0 + cht * 256];               \
      bf16x8 vf1 = *(const bf16x8*)&v_lds[CUR][ek1 + cht * 256];               \
      bf16x8 vf2 = *(const bf16x8*)&v_lds[CUR][ek2 + cht * 256];               \
      bf16x8 vf3 = *(const bf16x8*)&v_lds[CUR][ek3 + cht * 256];               \
      acc[cht] = mfma32(pf0, vf0, acc[cht]);                                   \
      acc[cht] = mfma32(pf1, vf1, acc[cht]);                                   \
      acc[cht] = mfma32(pf2, vf2, acc[cht]);                                   \
      acc[cht] = mfma32(pf3, vf3, acc[cht]);                                   \
    }                                                                          \
    if (pre) {                                                                 \
      *(uint4*)&v_lds[NXT][wr0] = sa0;                                         \
      *(uint4*)&v_lds[NXT][wr0 + 512] = sa1;                                   \
    }                                                                          \
  }

  #pragma unroll 1
  for (int tt = 0; tt < 32; ++tt) {
    ATTN_TILE(2 * tt, 0, 1);
    ATTN_TILE(2 * tt + 1, 1, 0);
  }

  // epilogue: normalize, gamma, residual
  const float inv_l = 1.f / l_run;
  f32x4 Iv[4];
  #pragma unroll
  for (int r = 0; r < 4; ++r) {
    Iv[0][r] = __shfl(inv_l, 4 * h + r);
    Iv[1][r] = __shfl(inv_l, 8 + 4 * h + r);
    Iv[2][r] = __shfl(inv_l, 16 + 4 * h + r);
    Iv[3][r] = __shfl(inv_l, 24 + 4 * h + r);
  }
  const float gm = gamma[0];
  #pragma unroll
  for (int cht = 0; cht < 4; ++cht) {
    const int ch = ch0 + cht * 32 + cl;
    const size_t rb = (size_t)(b * CC + ch) * NN + qw;
    #pragma unroll
    for (int j = 0; j < 4; ++j) {
      const size_t o = rb + 8 * j + 4 * h;
      f32x4 xv = *(const f32x4*)&x[o];
      f32x4 ov;
      #pragma unroll
      for (int r = 0; r < 4; ++r)
        ov[r] = gm * (acc[cht][4 * j + r] * Iv[j][r]) + xv[r];
      *(f32x4*)&out[o] = ov;
    }
  }
#undef ATTN_TILE
#undef PACKF
}

extern "C" void kernel_launch(void* const* d_in, const int* in_sizes, int n_in,
                              void* d_out, int out_size, void* d_ws, size_t ws_size,
                              hipStream_t stream) {
  (void)in_sizes; (void)n_in; (void)out_size; (void)ws_size;
  const float* x  = (const float*)d_in[0];
  const float* Wq = (const float*)d_in[1];
  const float* bq = (const float*)d_in[2];
  const float* Wk = (const float*)d_in[3];
  const float* bk = (const float*)d_in[4];
  const float* Wv = (const float*)d_in[5];
  const float* bv = (const float*)d_in[6];
  const float* gm = (const float*)d_in[7];
  float* out = (float*)d_out;

  char* ws = (char*)d_ws;
  u16* Xt = (u16*)ws;                                   // 16 MB
  u16* Qw = (u16*)(ws + (size_t)16 * 1024 * 1024);      //  2 MB
  u16* Kw = (u16*)(ws + (size_t)18 * 1024 * 1024);      //  2 MB
  u16* Vt = (u16*)(ws + (size_t)20 * 1024 * 1024);      // 16 MB

  k_transpose<<<dim3(NN / 32, CC / 32, BB), 256, 0, stream>>>(x, Xt);
  k_proj_qk<<<dim3(NN / 64, BB), 512, 0, stream>>>(Xt, Wq, bq, Wk, bk, Qw, Kw);
  k_proj_v<<<dim3(NN / 128, CC / 128, BB), 256, 0, stream>>>(Xt, Wv, bv, Vt);
  k_attn<<<dim3(256), 512, 0, stream>>>(Qw, Kw, Vt, x, gm, out);
}